// Round 3
// baseline (3708.039 us; speedup 1.0000x reference)
//
#include <hip/hip_runtime.h>
#include <math.h>

// PrattRNNLayer: ns_t = sqrt(cos^2(x_t@K) + sin^2(s_{t-1}@R)),
// out = ns*(1-ns^2), s_t = ns_t.  B=128, T=2048, D=128, fp32.
//
// Design (baseline, correctness-first):
//  - 1 block per batch row (128 blocks), 512 threads (8 waves, 2/SIMD).
//  - thread (d = tid>>2, kq = tid&3) owns quarter-columns K[32kq..+32][d],
//    R[32kq..+32][d] in REGISTERS (LDS-resident weights would cost
//    1024 cyc/step of LDS BW vs the 256-cyc FMA issue floor).
//  - state double-buffered in LDS (1 KiB), float4 reads -> 1 barrier/step.
//  - x row prefetched 1 step ahead into registers to hide load latency.
//  - 4-lane butterfly shfl_xor reduces the quarter-dot-products.
//  - precise cosf/sinf this round; native trig is the next lever pending
//    counter evidence + tolerance check.

constexpr int Bb = 128;
constexpr int Tt = 2048;
constexpr int Dd = 128;

__global__ __launch_bounds__(512, 2)
void pratt_rnn(const float* __restrict__ x,
               const float* __restrict__ Kmat,
               const float* __restrict__ Rmat,
               float* __restrict__ out)
{
    const int b   = blockIdx.x;
    const int tid = threadIdx.x;
    const int d   = tid >> 2;   // output feature this thread helps compute
    const int kq  = tid & 3;    // which k-quarter of the dot product
    const int k0  = kq << 5;    // 32*kq

    // Quarter-column weights in registers (one-time strided global loads).
    float Kr[32], Rr[32];
#pragma unroll
    for (int i = 0; i < 32; ++i) {
        Kr[i] = Kmat[(k0 + i) * Dd + d];
        Rr[i] = Rmat[(k0 + i) * Dd + d];
    }

    __shared__ float sbuf[2][Dd];
    if (tid < Dd) sbuf[0][tid] = 0.0f;   // s0 = zeros
    __syncthreads();

    const float* xb = x   + (size_t)b * Tt * Dd;
    float*       ob = out + (size_t)b * Tt * Dd;

    // prefetch x row 0 (this thread's quarter slice, 32 floats as 8x float4)
    float4 xv[8];
    {
        const float4* xr = reinterpret_cast<const float4*>(xb) + (k0 >> 2);
#pragma unroll
        for (int i = 0; i < 8; ++i) xv[i] = xr[i];
    }

    int cur = 0;
    for (int t = 0; t < Tt; ++t) {
        // prefetch next x row (clamped at the end; redundant re-read is harmless)
        float4 xn[8];
        {
            const int tn = (t + 1 < Tt) ? (t + 1) : t;
            const float4* xr = reinterpret_cast<const float4*>(xb + (size_t)tn * Dd) + (k0 >> 2);
#pragma unroll
            for (int i = 0; i < 8; ++i) xn[i] = xr[i];
        }

        // two quarter-GEMVs: km_part = x_t[k0..k0+31] . K[.., d]
        //                    rc_part = s  [k0..k0+31] . R[.., d]
        const float4* s4 = reinterpret_cast<const float4*>(&sbuf[cur][k0]);
        float ka0 = 0.f, ka1 = 0.f, ka2 = 0.f, ka3 = 0.f;
        float ra0 = 0.f, ra1 = 0.f, ra2 = 0.f, ra3 = 0.f;
#pragma unroll
        for (int i = 0; i < 8; ++i) {
            const float4 sv = s4[i];
            ka0 = fmaf(xv[i].x, Kr[4*i+0], ka0);
            ka1 = fmaf(xv[i].y, Kr[4*i+1], ka1);
            ka2 = fmaf(xv[i].z, Kr[4*i+2], ka2);
            ka3 = fmaf(xv[i].w, Kr[4*i+3], ka3);
            ra0 = fmaf(sv.x, Rr[4*i+0], ra0);
            ra1 = fmaf(sv.y, Rr[4*i+1], ra1);
            ra2 = fmaf(sv.z, Rr[4*i+2], ra2);
            ra3 = fmaf(sv.w, Rr[4*i+3], ra3);
        }
        float km = (ka0 + ka1) + (ka2 + ka3);
        float rc = (ra0 + ra1) + (ra2 + ra3);
        // 4-lane butterfly reduction (lanes 4d..4d+3 hold the 4 k-quarters)
        km += __shfl_xor(km, 1);
        km += __shfl_xor(km, 2);
        rc += __shfl_xor(rc, 1);
        rc += __shfl_xor(rc, 2);

        // nonlinearity (precise libm this round; native trig is a later lever)
        const float c  = cosf(km);
        const float s  = sinf(rc);
        const float ns = sqrtf(fmaf(c, c, s * s));
        const float o  = ns * (1.0f - ns * ns);

        const int nxt = cur ^ 1;
        if (kq == 0) sbuf[nxt][d] = ns;              // publish new state
        if (kq == 1) ob[(size_t)t * Dd + d] = o;     // write output
        __syncthreads();                              // one barrier per step

        cur = nxt;
#pragma unroll
        for (int i = 0; i < 8; ++i) xv[i] = xn[i];
    }
}

extern "C" void kernel_launch(void* const* d_in, const int* in_sizes, int n_in,
                              void* d_out, int out_size, void* d_ws, size_t ws_size,
                              hipStream_t stream)
{
    const float* x = (const float*)d_in[0];   // [128, 2048, 128] f32
    const float* K = (const float*)d_in[1];   // [128, 128] f32
    const float* R = (const float*)d_in[2];   // [128, 128] f32
    float* out = (float*)d_out;               // [128, 2048, 128] f32

    pratt_rnn<<<dim3(Bb), dim3(512), 0, stream>>>(x, K, R, out);
}

// Round 4
// 1952.363 us; speedup vs baseline: 1.8993x; 1.8993x over previous
//
#include <hip/hip_runtime.h>
#include <math.h>

// PrattRNNLayer: ns_t = sqrt(cos^2(x_t@K) + sin^2(s_{t-1}@R)), out = ns*(1-ns^2).
// B=128, T=2048, D=128, fp32.
//
// Round-3 restructure (evidence: VGPR_Count=80 vs ~150 needed -> spill/remat;
// VALUBusy 12.5%; 6.7e7 LDS bank conflicts):
//  K1 prepass: km = x@K for all (b,t) in parallel on 256 CUs (reference also
//     hoists this). Removes 64 weight regs + 64 x-prefetch regs from the
//     serial kernel -> no spill, and halves serial FMA work.
//  K2 serial: 1 block/row, 512 thr; thread (d=tid>>2, kq=tid&3) keeps only
//     Rr[32] in regs (~60 VGPR total). State chunk reads are per-thread
//     ROTATED (weights stored pre-rotated so register indices stay
//     compile-time) -> 4 kq-quarters hit disjoint LDS bank groups.

constexpr int Bb = 128;
constexpr int Tt = 2048;
constexpr int Dd = 128;
constexpr int ROWS_PER_BLK = 8;   // prepass rows per 256-thr block

// ---------- K1: km[i,:] = x[i,:] @ K, i = b*T + t ----------
__global__ __launch_bounds__(256)
void pratt_prepass(const float* __restrict__ x,
                   const float* __restrict__ Kmat,
                   float* __restrict__ km)
{
    const int i  = blockIdx.x * ROWS_PER_BLK + (threadIdx.x >> 5); // flat row
    const int d4 = threadIdx.x & 31;                               // float4 col
    const float*  xrow = x + (size_t)i * Dd;
    const float4* K4   = reinterpret_cast<const float4*>(Kmat);

    float4 acc = make_float4(0.f, 0.f, 0.f, 0.f);
#pragma unroll 4
    for (int k = 0; k < Dd; ++k) {
        const float  xk = xrow[k];          // 32 lanes broadcast same addr (L1)
        const float4 kv = K4[k * 32 + d4];  // coalesced; K is L2-resident
        acc.x = fmaf(xk, kv.x, acc.x);
        acc.y = fmaf(xk, kv.y, acc.y);
        acc.z = fmaf(xk, kv.z, acc.z);
        acc.w = fmaf(xk, kv.w, acc.w);
    }
    reinterpret_cast<float4*>(km)[(size_t)i * 32 + d4] = acc;      // coalesced
}

// ---------- K2: serial recurrence, one block per batch row ----------
__global__ __launch_bounds__(512, 2)
void pratt_rnn(const float* __restrict__ km,
               const float* __restrict__ Rmat,
               float* __restrict__ out)
{
    const int tid = threadIdx.x;
    const int d   = tid >> 2;   // output feature
    const int kq  = tid & 3;    // k-quarter
    const int k0  = kq << 5;
    const int rot = kq << 1;    // chunk rotation = 2*kq (disjoint bank groups)

    // Weights stored PRE-ROTATED: slot ii holds global chunk (ii+rot)&7, so
    // main-loop register indices are compile-time (no scratch; rule #20).
    float Rr[32];
#pragma unroll
    for (int ii = 0; ii < 8; ++ii) {
        const int c = (ii + rot) & 7;
#pragma unroll
        for (int j = 0; j < 4; ++j)
            Rr[4*ii + j] = Rmat[(k0 + 4*c + j) * Dd + d];
    }

    __shared__ float sbuf[2][Dd];
    if (tid < Dd) sbuf[0][tid] = 0.0f;   // s0 = zeros
    __syncthreads();

    const float* kmb = km  + (size_t)blockIdx.x * Tt * Dd;
    float*       ob  = out + (size_t)blockIdx.x * Tt * Dd;

    float kmv = kmb[d];   // km for t=0 (4 threads per d share the load)
    int cur = 0;
    for (int t = 0; t < Tt; ++t) {
        // prefetch km for t+1; consumed next iteration (latency hidden)
        const int tn = (t + 1 < Tt) ? t + 1 : t;
        const float kmn = kmb[(size_t)tn * Dd + d];

        // rc_part = s[k0..k0+31] . R[.., d], chunks in rotated order
        float ra0=0.f, ra1=0.f, ra2=0.f, ra3=0.f;
#pragma unroll
        for (int ii = 0; ii < 8; ++ii) {
            const int c = (ii + rot) & 7;  // runtime addr, static reg index
            const float4 sv = *reinterpret_cast<const float4*>(&sbuf[cur][k0 + 4*c]);
            ra0 = fmaf(sv.x, Rr[4*ii+0], ra0);
            ra1 = fmaf(sv.y, Rr[4*ii+1], ra1);
            ra2 = fmaf(sv.z, Rr[4*ii+2], ra2);
            ra3 = fmaf(sv.w, Rr[4*ii+3], ra3);
        }
        float rc = (ra0 + ra1) + (ra2 + ra3);
        rc += __shfl_xor(rc, 1);   // reduce across the 4 kq lanes
        rc += __shfl_xor(rc, 2);

        const float cc = cosf(kmv);
        const float ss = sinf(rc);
        const float ns = sqrtf(fmaf(cc, cc, ss * ss));
        const float o  = ns * (1.0f - ns * ns);

        const int nxt = cur ^ 1;
        if (kq == 0) sbuf[nxt][d] = ns;            // publish state
        if (kq == 1) ob[(size_t)t * Dd + d] = o;   // write output
        __syncthreads();                            // one barrier per step
        cur = nxt;
        kmv = kmn;
    }
}

// ---------- fallback (proven-correct fused kernel) if ws is too small ----------
__global__ __launch_bounds__(512, 2)
void pratt_fused(const float* __restrict__ x,
                 const float* __restrict__ Kmat,
                 const float* __restrict__ Rmat,
                 float* __restrict__ out)
{
    const int b   = blockIdx.x;
    const int tid = threadIdx.x;
    const int d   = tid >> 2;
    const int kq  = tid & 3;
    const int k0  = kq << 5;

    float Kr[32], Rr[32];
#pragma unroll
    for (int i = 0; i < 32; ++i) {
        Kr[i] = Kmat[(k0 + i) * Dd + d];
        Rr[i] = Rmat[(k0 + i) * Dd + d];
    }
    __shared__ float sbuf[2][Dd];
    if (tid < Dd) sbuf[0][tid] = 0.0f;
    __syncthreads();

    const float* xb = x   + (size_t)b * Tt * Dd;
    float*       ob = out + (size_t)b * Tt * Dd;
    int cur = 0;
    for (int t = 0; t < Tt; ++t) {
        const float4* xr = reinterpret_cast<const float4*>(xb + (size_t)t * Dd) + (k0 >> 2);
        const float4* s4 = reinterpret_cast<const float4*>(&sbuf[cur][k0]);
        float ka = 0.f, ra = 0.f;
#pragma unroll
        for (int i = 0; i < 8; ++i) {
            const float4 xv = xr[i];
            const float4 sv = s4[i];
            ka = fmaf(xv.x, Kr[4*i+0], ka); ka = fmaf(xv.y, Kr[4*i+1], ka);
            ka = fmaf(xv.z, Kr[4*i+2], ka); ka = fmaf(xv.w, Kr[4*i+3], ka);
            ra = fmaf(sv.x, Rr[4*i+0], ra); ra = fmaf(sv.y, Rr[4*i+1], ra);
            ra = fmaf(sv.z, Rr[4*i+2], ra); ra = fmaf(sv.w, Rr[4*i+3], ra);
        }
        ka += __shfl_xor(ka, 1); ka += __shfl_xor(ka, 2);
        ra += __shfl_xor(ra, 1); ra += __shfl_xor(ra, 2);
        const float cc = cosf(ka), ss = sinf(ra);
        const float ns = sqrtf(fmaf(cc, cc, ss * ss));
        const float o  = ns * (1.0f - ns * ns);
        const int nxt = cur ^ 1;
        if (kq == 0) sbuf[nxt][d] = ns;
        if (kq == 1) ob[(size_t)t * Dd + d] = o;
        __syncthreads();
        cur = nxt;
    }
}

extern "C" void kernel_launch(void* const* d_in, const int* in_sizes, int n_in,
                              void* d_out, int out_size, void* d_ws, size_t ws_size,
                              hipStream_t stream)
{
    const float* x = (const float*)d_in[0];   // [128, 2048, 128] f32
    const float* K = (const float*)d_in[1];   // [128, 128] f32
    const float* R = (const float*)d_in[2];   // [128, 128] f32
    float* out = (float*)d_out;

    const size_t km_bytes = (size_t)Bb * Tt * Dd * sizeof(float);  // 128 MB
    if (ws_size >= km_bytes) {
        float* km = (float*)d_ws;
        pratt_prepass<<<dim3(Bb * Tt / ROWS_PER_BLK), dim3(256), 0, stream>>>(x, K, km);
        pratt_rnn<<<dim3(Bb), dim3(512), 0, stream>>>(km, R, out);
    } else {
        pratt_fused<<<dim3(Bb), dim3(512), 0, stream>>>(x, K, R, out);
    }
}

// Round 11
// 1406.115 us; speedup vs baseline: 2.6371x; 1.3885x over previous
//
#include <hip/hip_runtime.h>
#include <math.h>

// PrattRNNLayer: ns_t = sqrt(cos^2(x_t@K) + sin^2(s_{t-1}@R)), out = ns*(1-ns^2).
// B=128, T=2048, D=128, fp32.
//
// Round-9: fix compile error only — __sqrtf is not a HIP device function
// (resolved to glibc host __sqrt); use __builtin_amdgcn_sqrtf (v_sqrt_f32).
// Rest identical to the audited R5 kernel:
//  K1 prepass v2: K staged in LDS once/block, 8x8 register tile/thread,
//     128 rows/block -> K L2 traffic /128, FMA density ~90%.
//  K2 serial: native __cosf/__sinf (v_cos/v_sin; ~3 inst vs ~30 libm).

constexpr int Bb = 128;
constexpr int Tt = 2048;
constexpr int Dd = 128;
constexpr int PP_ROWS = 128;   // prepass rows per block

// ---------- K1: km[i,:] = x[i,:] @ K, i = b*T + t ----------
__global__ __launch_bounds__(256, 2)
void pratt_prepass(const float* __restrict__ x,
                   const float* __restrict__ Kmat,
                   float* __restrict__ km)
{
    __shared__ float Ks[Dd][Dd];   // 64 KiB: K staged ONCE per block
    {
        const float4* Kg  = reinterpret_cast<const float4*>(Kmat);
        float4*       KsV = reinterpret_cast<float4*>(&Ks[0][0]);
#pragma unroll
        for (int j = 0; j < 16; ++j)
            KsV[threadIdx.x + j * 256] = Kg[threadIdx.x + j * 256];
    }
    __syncthreads();

    const int  rgrp = threadIdx.x >> 4;                    // 0..15 -> 8 rows
    const int  cgrp = threadIdx.x & 15;                    // 0..15 -> 8 cols
    const int  c0   = cgrp << 3;
    const long row0 = (long)blockIdx.x * PP_ROWS + (long)rgrp * 8;

    const float4* xr[8];
#pragma unroll
    for (int r = 0; r < 8; ++r)
        xr[r] = reinterpret_cast<const float4*>(x + (size_t)(row0 + r) * Dd);

    float acc[8][8];
#pragma unroll
    for (int r = 0; r < 8; ++r)
#pragma unroll
        for (int c = 0; c < 8; ++c) acc[r][c] = 0.f;

    for (int k4 = 0; k4 < Dd / 4; ++k4) {
        float4 xq[8];
#pragma unroll
        for (int r = 0; r < 8; ++r) xq[r] = xr[r][k4];     // broadcast within rgrp
        float4 kf[4][2];
#pragma unroll
        for (int kk = 0; kk < 4; ++kk) {
            const float* krow = &Ks[k4 * 4 + kk][c0];
            kf[kk][0] = *reinterpret_cast<const float4*>(krow);
            kf[kk][1] = *reinterpret_cast<const float4*>(krow + 4);
        }
#pragma unroll
        for (int kk = 0; kk < 4; ++kk) {
#pragma unroll
            for (int r = 0; r < 8; ++r) {
                const float xv = (kk == 0) ? xq[r].x : (kk == 1) ? xq[r].y
                               : (kk == 2) ? xq[r].z : xq[r].w;
                acc[r][0] = fmaf(xv, kf[kk][0].x, acc[r][0]);
                acc[r][1] = fmaf(xv, kf[kk][0].y, acc[r][1]);
                acc[r][2] = fmaf(xv, kf[kk][0].z, acc[r][2]);
                acc[r][3] = fmaf(xv, kf[kk][0].w, acc[r][3]);
                acc[r][4] = fmaf(xv, kf[kk][1].x, acc[r][4]);
                acc[r][5] = fmaf(xv, kf[kk][1].y, acc[r][5]);
                acc[r][6] = fmaf(xv, kf[kk][1].z, acc[r][6]);
                acc[r][7] = fmaf(xv, kf[kk][1].w, acc[r][7]);
            }
        }
    }
#pragma unroll
    for (int r = 0; r < 8; ++r) {
        float4* o = reinterpret_cast<float4*>(km + (size_t)(row0 + r) * Dd + c0);
        o[0] = make_float4(acc[r][0], acc[r][1], acc[r][2], acc[r][3]);
        o[1] = make_float4(acc[r][4], acc[r][5], acc[r][6], acc[r][7]);
    }
}

// ---------- K2: serial recurrence, one block per batch row ----------
__global__ __launch_bounds__(512, 2)
void pratt_rnn(const float* __restrict__ km,
               const float* __restrict__ Rmat,
               float* __restrict__ out)
{
    const int tid = threadIdx.x;
    const int d   = tid >> 2;   // output feature
    const int kq  = tid & 3;    // k-quarter
    const int k0  = kq << 5;
    const int rot = kq << 1;    // chunk rotation (disjoint bank groups)

    // Weights PRE-ROTATED so main-loop register indices stay compile-time.
    float Rr[32];
#pragma unroll
    for (int ii = 0; ii < 8; ++ii) {
        const int c = (ii + rot) & 7;
#pragma unroll
        for (int j = 0; j < 4; ++j)
            Rr[4*ii + j] = Rmat[(k0 + 4*c + j) * Dd + d];
    }

    __shared__ float sbuf[2][Dd];
    if (tid < Dd) sbuf[0][tid] = 0.0f;   // s0 = zeros
    __syncthreads();

    const float* kmb = km  + (size_t)blockIdx.x * Tt * Dd;
    float*       ob  = out + (size_t)blockIdx.x * Tt * Dd;

    float kmv = kmb[d];   // km for t=0
    int cur = 0;
    for (int t = 0; t < Tt; ++t) {
        const int tn = (t + 1 < Tt) ? t + 1 : t;
        const float kmn = kmb[(size_t)tn * Dd + d];   // prefetch t+1

        float ra0=0.f, ra1=0.f, ra2=0.f, ra3=0.f;
#pragma unroll
        for (int ii = 0; ii < 8; ++ii) {
            const int c = (ii + rot) & 7;  // runtime addr, static reg index
            const float4 sv = *reinterpret_cast<const float4*>(&sbuf[cur][k0 + 4*c]);
            ra0 = fmaf(sv.x, Rr[4*ii+0], ra0);
            ra1 = fmaf(sv.y, Rr[4*ii+1], ra1);
            ra2 = fmaf(sv.z, Rr[4*ii+2], ra2);
            ra3 = fmaf(sv.w, Rr[4*ii+3], ra3);
        }
        float rc = (ra0 + ra1) + (ra2 + ra3);
        rc += __shfl_xor(rc, 1);
        rc += __shfl_xor(rc, 2);

        // native trig/sqrt (v_cos/v_sin/v_sqrt): ~3 inst each vs ~30 libm
        const float cc = __cosf(kmv);
        const float ss = __sinf(rc);
        const float ns = __builtin_amdgcn_sqrtf(fmaf(cc, cc, ss * ss));
        const float o  = ns * (1.0f - ns * ns);

        const int nxt = cur ^ 1;
        if (kq == 0) sbuf[nxt][d] = ns;            // publish state
        if (kq == 1) ob[(size_t)t * Dd + d] = o;   // write output
        __syncthreads();                            // one barrier per step
        cur = nxt;
        kmv = kmn;
    }
}

// ---------- fallback (proven-correct fused kernel) if ws is too small ----------
__global__ __launch_bounds__(512, 2)
void pratt_fused(const float* __restrict__ x,
                 const float* __restrict__ Kmat,
                 const float* __restrict__ Rmat,
                 float* __restrict__ out)
{
    const int b   = blockIdx.x;
    const int tid = threadIdx.x;
    const int d   = tid >> 2;
    const int kq  = tid & 3;
    const int k0  = kq << 5;

    float Kr[32], Rr[32];
#pragma unroll
    for (int i = 0; i < 32; ++i) {
        Kr[i] = Kmat[(k0 + i) * Dd + d];
        Rr[i] = Rmat[(k0 + i) * Dd + d];
    }
    __shared__ float sbuf[2][Dd];
    if (tid < Dd) sbuf[0][tid] = 0.0f;
    __syncthreads();

    const float* xb = x   + (size_t)b * Tt * Dd;
    float*       ob = out + (size_t)b * Tt * Dd;
    int cur = 0;
    for (int t = 0; t < Tt; ++t) {
        const float4* xr = reinterpret_cast<const float4*>(xb + (size_t)t * Dd) + (k0 >> 2);
        const float4* s4 = reinterpret_cast<const float4*>(&sbuf[cur][k0]);
        float ka = 0.f, ra = 0.f;
#pragma unroll
        for (int i = 0; i < 8; ++i) {
            const float4 xv = xr[i];
            const float4 sv = s4[i];
            ka = fmaf(xv.x, Kr[4*i+0], ka); ka = fmaf(xv.y, Kr[4*i+1], ka);
            ka = fmaf(xv.z, Kr[4*i+2], ka); ka = fmaf(xv.w, Kr[4*i+3], ka);
            ra = fmaf(sv.x, Rr[4*i+0], ra); ra = fmaf(sv.y, Rr[4*i+1], ra);
            ra = fmaf(sv.z, Rr[4*i+2], ra); ra = fmaf(sv.w, Rr[4*i+3], ra);
        }
        ka += __shfl_xor(ka, 1); ka += __shfl_xor(ka, 2);
        ra += __shfl_xor(ra, 1); ra += __shfl_xor(ra, 2);
        const float cc = cosf(ka), ss = sinf(ra);
        const float ns = sqrtf(fmaf(cc, cc, ss * ss));
        const float o  = ns * (1.0f - ns * ns);
        const int nxt = cur ^ 1;
        if (kq == 0) sbuf[nxt][d] = ns;
        if (kq == 1) ob[(size_t)t * Dd + d] = o;
        __syncthreads();
        cur = nxt;
    }
}

extern "C" void kernel_launch(void* const* d_in, const int* in_sizes, int n_in,
                              void* d_out, int out_size, void* d_ws, size_t ws_size,
                              hipStream_t stream)
{
    const float* x = (const float*)d_in[0];   // [128, 2048, 128] f32
    const float* K = (const float*)d_in[1];   // [128, 128] f32
    const float* R = (const float*)d_in[2];   // [128, 128] f32
    float* out = (float*)d_out;

    const size_t km_bytes = (size_t)Bb * Tt * Dd * sizeof(float);  // 128 MB
    if (ws_size >= km_bytes) {
        float* km = (float*)d_ws;
        pratt_prepass<<<dim3(Bb * Tt / PP_ROWS), dim3(256), 0, stream>>>(x, K, km);
        pratt_rnn<<<dim3(Bb), dim3(512), 0, stream>>>(km, R, out);
    } else {
        pratt_fused<<<dim3(Bb), dim3(512), 0, stream>>>(x, K, R, out);
    }
}

// Round 13
// 1056.400 us; speedup vs baseline: 3.5101x; 1.3310x over previous
//
#include <hip/hip_runtime.h>
#include <math.h>

// PrattRNNLayer: ns_t = sqrt(cos^2(x_t@K) + sin^2(s_{t-1}@R)), out = ns*(1-ns^2).
// B=128, T=2048, D=128, fp32.
//
// Round-12 (evidence: R4->R11 native trig halved VALUBusy (34.6->17.6%) with
// ZERO duration change -> serial step pinned ~1435cyc by fixed latency, and
// the dominant term is the vmcnt(0) drain the compiler emits before s_barrier:
// the per-step global km prefetch + out store serialize an HBM round-trip
// into EVERY step):
//  K1 prepass: unchanged math, but writes km TRANSPOSED kmT[b][d][t] so each
//     thread's next 16 steps of km are 64B contiguous.
//  K2 serial: 16-step groups — prefetch next group's km (4x float4) at group
//     top, buffer 16 outputs in regs, store once per group. Barrier drain
//     amortized 16x (~900 -> ~40 cyc/step). Full unroll -> static reg idx.

constexpr int Bb = 128;
constexpr int Tt = 2048;
constexpr int Dd = 128;
constexpr int PP_ROWS = 128;   // prepass rows per block
constexpr int GROUP = 16;      // serial steps per km-prefetch group

// ---------- K1: kmT[b][d][t] = sum_k x[b,t,k] K[k,d] ----------
__global__ __launch_bounds__(256, 2)
void pratt_prepass(const float* __restrict__ x,
                   const float* __restrict__ Kmat,
                   float* __restrict__ kmT)
{
    __shared__ float Ks[Dd][Dd];   // 64 KiB: K staged ONCE per block
    {
        const float4* Kg  = reinterpret_cast<const float4*>(Kmat);
        float4*       KsV = reinterpret_cast<float4*>(&Ks[0][0]);
#pragma unroll
        for (int j = 0; j < 16; ++j)
            KsV[threadIdx.x + j * 256] = Kg[threadIdx.x + j * 256];
    }
    __syncthreads();

    const int  rgrp = threadIdx.x >> 4;                    // 0..15 -> 8 rows
    const int  cgrp = threadIdx.x & 15;                    // 0..15 -> 8 cols
    const int  c0   = cgrp << 3;
    const long row0 = (long)blockIdx.x * PP_ROWS + (long)rgrp * 8;

    const float4* xr[8];
#pragma unroll
    for (int r = 0; r < 8; ++r)
        xr[r] = reinterpret_cast<const float4*>(x + (size_t)(row0 + r) * Dd);

    float acc[8][8];
#pragma unroll
    for (int r = 0; r < 8; ++r)
#pragma unroll
        for (int c = 0; c < 8; ++c) acc[r][c] = 0.f;

    for (int k4 = 0; k4 < Dd / 4; ++k4) {
        float4 xq[8];
#pragma unroll
        for (int r = 0; r < 8; ++r) xq[r] = xr[r][k4];
        float4 kf[4][2];
#pragma unroll
        for (int kk = 0; kk < 4; ++kk) {
            const float* krow = &Ks[k4 * 4 + kk][c0];
            kf[kk][0] = *reinterpret_cast<const float4*>(krow);
            kf[kk][1] = *reinterpret_cast<const float4*>(krow + 4);
        }
#pragma unroll
        for (int kk = 0; kk < 4; ++kk) {
#pragma unroll
            for (int r = 0; r < 8; ++r) {
                const float xv = (kk == 0) ? xq[r].x : (kk == 1) ? xq[r].y
                               : (kk == 2) ? xq[r].z : xq[r].w;
                acc[r][0] = fmaf(xv, kf[kk][0].x, acc[r][0]);
                acc[r][1] = fmaf(xv, kf[kk][0].y, acc[r][1]);
                acc[r][2] = fmaf(xv, kf[kk][0].z, acc[r][2]);
                acc[r][3] = fmaf(xv, kf[kk][0].w, acc[r][3]);
                acc[r][4] = fmaf(xv, kf[kk][1].x, acc[r][4]);
                acc[r][5] = fmaf(xv, kf[kk][1].y, acc[r][5]);
                acc[r][6] = fmaf(xv, kf[kk][1].z, acc[r][6]);
                acc[r][7] = fmaf(xv, kf[kk][1].w, acc[r][7]);
            }
        }
    }

    // transposed store: 16 blocks per batch (2048/128), block fully in one b
    const int b   = blockIdx.x >> 4;
    const int t00 = (blockIdx.x & 15) * PP_ROWS + rgrp * 8;   // t of r=0
#pragma unroll
    for (int c = 0; c < 8; ++c) {
        float* p = kmT + ((size_t)b * Dd + (c0 + c)) * Tt + t00;
        *reinterpret_cast<float4*>(p)     = make_float4(acc[0][c], acc[1][c], acc[2][c], acc[3][c]);
        *reinterpret_cast<float4*>(p + 4) = make_float4(acc[4][c], acc[5][c], acc[6][c], acc[7][c]);
    }
}

// ---------- K2: serial recurrence, one block per batch row ----------
__global__ __launch_bounds__(512, 1)
void pratt_rnn(const float* __restrict__ kmT,
               const float* __restrict__ Rmat,
               float* __restrict__ out)
{
    const int tid = threadIdx.x;
    const int d   = tid >> 2;   // output feature
    const int kq  = tid & 3;    // k-quarter
    const int k0  = kq << 5;
    const int rot = kq << 1;    // chunk rotation (disjoint bank groups)

    // Weights PRE-ROTATED so main-loop register indices stay compile-time.
    float Rr[32];
#pragma unroll
    for (int ii = 0; ii < 8; ++ii) {
        const int c = (ii + rot) & 7;
#pragma unroll
        for (int j = 0; j < 4; ++j)
            Rr[4*ii + j] = Rmat[(k0 + 4*c + j) * Dd + d];
    }

    __shared__ float sbuf[2][Dd];
    if (tid < Dd) sbuf[0][tid] = 0.0f;   // s0 = zeros
    __syncthreads();

    const float* kmd = kmT + ((size_t)blockIdx.x * Dd + d) * Tt;  // this d's km row
    float*       ob  = out + (size_t)blockIdx.x * Tt * Dd;

    // preload group 0 (16 km values = 4 x float4, 64B contiguous)
    float4 cur0 = *reinterpret_cast<const float4*>(kmd + 0);
    float4 cur1 = *reinterpret_cast<const float4*>(kmd + 4);
    float4 cur2 = *reinterpret_cast<const float4*>(kmd + 8);
    float4 cur3 = *reinterpret_cast<const float4*>(kmd + 12);

    for (int g = 0; g < Tt / GROUP; ++g) {
        // issue next group's loads; drained at this group's FIRST barrier
        // (one residual stall per 16 steps instead of one per step)
        const int gn = (g + 1 < Tt / GROUP) ? g + 1 : g;
        const float* pn = kmd + (size_t)gn * GROUP;
        const float4 nx0 = *reinterpret_cast<const float4*>(pn + 0);
        const float4 nx1 = *reinterpret_cast<const float4*>(pn + 4);
        const float4 nx2 = *reinterpret_cast<const float4*>(pn + 8);
        const float4 nx3 = *reinterpret_cast<const float4*>(pn + 12);

        float ovals[GROUP];          // static-indexed under full unroll
        const int tbase = g * GROUP; // global t of j=0 (even -> parity static)

#pragma unroll
        for (int j = 0; j < GROUP; ++j) {
            // compile-time km selection (folds under unroll)
            const float4 qs  = (j < 4) ? cur0 : (j < 8) ? cur1 : (j < 12) ? cur2 : cur3;
            const int    jm  = j & 3;
            const float  kmv = (jm == 0) ? qs.x : (jm == 1) ? qs.y : (jm == 2) ? qs.z : qs.w;
            const int    rb  = j & 1;  // read buffer parity (GROUP even)

            float ra0=0.f, ra1=0.f, ra2=0.f, ra3=0.f;
#pragma unroll
            for (int ii = 0; ii < 8; ++ii) {
                const int c = (ii + rot) & 7;  // runtime addr, static reg index
                const float4 sv = *reinterpret_cast<const float4*>(&sbuf[rb][k0 + 4*c]);
                ra0 = fmaf(sv.x, Rr[4*ii+0], ra0);
                ra1 = fmaf(sv.y, Rr[4*ii+1], ra1);
                ra2 = fmaf(sv.z, Rr[4*ii+2], ra2);
                ra3 = fmaf(sv.w, Rr[4*ii+3], ra3);
            }
            float rc = (ra0 + ra1) + (ra2 + ra3);
            rc += __shfl_xor(rc, 1);
            rc += __shfl_xor(rc, 2);

            const float cc = __cosf(kmv);
            const float ss = __sinf(rc);
            const float ns = __builtin_amdgcn_sqrtf(fmaf(cc, cc, ss * ss));
            ovals[j] = ns * (1.0f - ns * ns);

            if (kq == 0) sbuf[rb ^ 1][d] = ns;   // publish state
            __syncthreads();                      // one barrier per step
        }

        // one batched output store per group (drained at next group's barrier)
        if (kq == 1) {
#pragma unroll
            for (int j = 0; j < GROUP; ++j)
                ob[(size_t)(tbase + j) * Dd + d] = ovals[j];
        }

        cur0 = nx0; cur1 = nx1; cur2 = nx2; cur3 = nx3;
    }
}

// ---------- fallback (proven-correct fused kernel) if ws is too small ----------
__global__ __launch_bounds__(512, 2)
void pratt_fused(const float* __restrict__ x,
                 const float* __restrict__ Kmat,
                 const float* __restrict__ Rmat,
                 float* __restrict__ out)
{
    const int b   = blockIdx.x;
    const int tid = threadIdx.x;
    const int d   = tid >> 2;
    const int kq  = tid & 3;
    const int k0  = kq << 5;

    float Kr[32], Rr[32];
#pragma unroll
    for (int i = 0; i < 32; ++i) {
        Kr[i] = Kmat[(k0 + i) * Dd + d];
        Rr[i] = Rmat[(k0 + i) * Dd + d];
    }
    __shared__ float sbuf[2][Dd];
    if (tid < Dd) sbuf[0][tid] = 0.0f;
    __syncthreads();

    const float* xb = x   + (size_t)b * Tt * Dd;
    float*       ob = out + (size_t)b * Tt * Dd;
    int cur = 0;
    for (int t = 0; t < Tt; ++t) {
        const float4* xr = reinterpret_cast<const float4*>(xb + (size_t)t * Dd) + (k0 >> 2);
        const float4* s4 = reinterpret_cast<const float4*>(&sbuf[cur][k0]);
        float ka = 0.f, ra = 0.f;
#pragma unroll
        for (int i = 0; i < 8; ++i) {
            const float4 xv = xr[i];
            const float4 sv = s4[i];
            ka = fmaf(xv.x, Kr[4*i+0], ka); ka = fmaf(xv.y, Kr[4*i+1], ka);
            ka = fmaf(xv.z, Kr[4*i+2], ka); ka = fmaf(xv.w, Kr[4*i+3], ka);
            ra = fmaf(sv.x, Rr[4*i+0], ra); ra = fmaf(sv.y, Rr[4*i+1], ra);
            ra = fmaf(sv.z, Rr[4*i+2], ra); ra = fmaf(sv.w, Rr[4*i+3], ra);
        }
        ka += __shfl_xor(ka, 1); ka += __shfl_xor(ka, 2);
        ra += __shfl_xor(ra, 1); ra += __shfl_xor(ra, 2);
        const float cc = cosf(ka), ss = sinf(ra);
        const float ns = sqrtf(fmaf(cc, cc, ss * ss));
        const float o  = ns * (1.0f - ns * ns);
        const int nxt = cur ^ 1;
        if (kq == 0) sbuf[nxt][d] = ns;
        if (kq == 1) ob[(size_t)t * Dd + d] = o;
        __syncthreads();
        cur = nxt;
    }
}

extern "C" void kernel_launch(void* const* d_in, const int* in_sizes, int n_in,
                              void* d_out, int out_size, void* d_ws, size_t ws_size,
                              hipStream_t stream)
{
    const float* x = (const float*)d_in[0];   // [128, 2048, 128] f32
    const float* K = (const float*)d_in[1];   // [128, 128] f32
    const float* R = (const float*)d_in[2];   // [128, 128] f32
    float* out = (float*)d_out;

    const size_t km_bytes = (size_t)Bb * Tt * Dd * sizeof(float);  // 128 MB
    if (ws_size >= km_bytes) {
        float* kmT = (float*)d_ws;
        pratt_prepass<<<dim3(Bb * Tt / PP_ROWS), dim3(256), 0, stream>>>(x, K, kmT);
        pratt_rnn<<<dim3(Bb), dim3(512), 0, stream>>>(kmT, R, out);
    } else {
        pratt_fused<<<dim3(Bb), dim3(512), 0, stream>>>(x, K, R, out);
    }
}